// Round 6
// baseline (118.887 us; speedup 1.0000x reference)
//
#include <hip/hip_runtime.h>

typedef __attribute__((ext_vector_type(8))) _Float16 half8;
typedef __attribute__((ext_vector_type(4))) float floatx4;

constexpr int NB  = 2;
constexpr int CC  = 64;
constexpr int DD  = 16;
constexpr int HH  = 32;
constexpr int WW  = 32;
constexpr int KN_ = 27;
constexpr int OC  = 64;
constexpr int DHW = DD * HH * WW;   // 16384
constexpr int TP  = 16;             // positions per block

__device__ __forceinline__ unsigned short f2h(float f) {
    _Float16 h = (_Float16)f;
    return *(unsigned short*)&h;
}

// ---------------------------------------------------------------------------
// Prep kernel (merged):
//  blocks [0, 512)   : NCDHW f32 -> NDHWC f16  (64 ch contiguous per voxel)
//  blocks [512, 944) : weight (o,c,k) f32 -> f16 MFMA A-fragment stream
//    wf[(((k*2+cc)*4+ot)*64 + l)*8 + i] = W[o=ot*16+(l&15)][c=cc*32+(l>>4)*8+i][k]
__global__ __launch_bounds__(256) void k_prep(const float* __restrict__ in,
                                              const float* __restrict__ w,
                                              unsigned int* __restrict__ outu,
                                              unsigned short* __restrict__ wf) {
    int bid = blockIdx.x;
    int t = threadIdx.x;
    if (bid < 512) {
        __shared__ float tile[64][65];
        int n  = bid >> 8;
        int v0 = (bid & 255) << 6;
        int lane = t & 63, row = t >> 6;
#pragma unroll
        for (int i = 0; i < 16; ++i) {
            int c = (i << 2) + row;
            tile[c][lane] = in[(size_t)(n * CC + c) * DHW + v0 + lane];
        }
        __syncthreads();
#pragma unroll
        for (int i = 0; i < 8; ++i) {
            int flat = i * 256 + t;
            int v = flat >> 5, cd = flat & 31;
            unsigned int lo = f2h(tile[2 * cd][v]);
            unsigned int hi = f2h(tile[2 * cd + 1][v]);
            outu[(size_t)(n * DHW + v0 + v) * 32 + cd] = lo | (hi << 16);
        }
    } else {
        int f = (bid - 512) * 256 + t;   // 110592 total
        int i  = f & 7;
        int l  = (f >> 3) & 63;
        int ot = (f >> 9) & 3;
        int cc = (f >> 11) & 1;
        int k  = f >> 12;
        int o = ot * 16 + (l & 15);
        int c = cc * 32 + ((l >> 4) << 3) + i;
        wf[f] = f2h(w[(o * CC + c) * KN_ + k]);
    }
}

// ---------------------------------------------------------------------------
// Wave-specialized pipelined deformable conv:
// 256 threads (4 waves), 16 positions/block, all 27 taps.
// Pair (k+1)&1 samples tap k+1 while all waves MFMA tap k. S triple-buffered,
// one barrier per tap. W fragments prefetched one tap ahead in registers.
__global__ __launch_bounds__(256, 5) void k_main(const unsigned short* __restrict__ inp,
                                                 const unsigned short* __restrict__ wf,
                                                 const float* __restrict__ offs,
                                                 float* __restrict__ out) {
    __shared__ unsigned short S[3 * TP * 64];      // 6KB: 3 bufs of [p16][c64] f16, chunk-XOR swz
    __shared__ unsigned int   SU[KN_ * TP * 8];    // 13.5KB: 32B rec = {u16 vox[8], f16 w[8]}

    int t   = threadIdx.x;
    int bid = blockIdx.x;
    int n   = (bid >> 2) & 1;                      // XCDs 0-3 -> n=0, 4-7 -> n=1 (L2 locality)
    int idx = ((bid >> 3) << 2) | (bid & 3);       // 0..1023
    int p0  = idx << 4;

    int pair = t >> 7;                             // wave-pair id (uniform per wave)
    int tl   = t & 127;
    int sp   = tl >> 3;                            // 0..15 position
    int cg   = tl & 7;                             // channel chunk (16B of 128B voxel row)

    int w  = t >> 6;                               // wave id 0..3 -> o-tile
    int l  = t & 63;
    int lrow = l & 15, lk = l >> 4;

    const float* offb = offs + (size_t)n * (3 * KN_) * DHW + p0;
    const char*  inb  = (const char*)(inp + ((size_t)n * DHW << 6));

    floatx4 acc = {0.f, 0.f, 0.f, 0.f};

    const int cgo   = cg << 4;
    const int woff  = sp * 64 + ((cg ^ (sp & 7)) << 3);            // ushort units
    const int roff0 = lrow * 64 + (((0 | lk) ^ (lrow & 7)) << 3);
    const int roff1 = lrow * 64 + (((4 | lk) ^ (lrow & 7)) << 3);

    // ---- setup: all 432 (k,p) sampling records, coordinate math once ----
    for (int si = t; si < KN_ * TP; si += 256) {
        int k = si >> 4, p = si & 15;
        int pa = p0 + p;
        int dpos = pa >> 10, hpos = (pa >> 5) & 31, wpos = pa & 31;

        float oz = offb[(k * 3 + 0) * DHW + p];
        float oy = offb[(k * 3 + 1) * DHW + p];
        float ox = offb[(k * 3 + 2) * DHW + p];
        float ix = ((float)wpos + ox) * (32.0f / 31.0f) - 0.5f;
        float iy = ((float)hpos + oy) * (32.0f / 31.0f) - 0.5f;
        float iz = ((float)dpos + oz) * (16.0f / 15.0f) - 0.5f;
        float xf = floorf(ix), yf = floorf(iy), zf = floorf(iz);
        float fx = ix - xf, fy = iy - yf, fz = iz - zf;
        int x0 = (int)xf, y0 = (int)yf, z0 = (int)zf;

        float wx0 = ((unsigned)x0       < (unsigned)WW) ? 1.f - fx : 0.f;
        float wx1 = ((unsigned)(x0 + 1) < (unsigned)WW) ? fx       : 0.f;
        float wy0 = ((unsigned)y0       < (unsigned)HH) ? 1.f - fy : 0.f;
        float wy1 = ((unsigned)(y0 + 1) < (unsigned)HH) ? fy       : 0.f;
        float wz0 = ((unsigned)z0       < (unsigned)DD) ? 1.f - fz : 0.f;
        float wz1 = ((unsigned)(z0 + 1) < (unsigned)DD) ? fz       : 0.f;

        int xc0 = min(max(x0, 0), WW - 1), xc1 = min(max(x0 + 1, 0), WW - 1);
        int yc0 = min(max(y0, 0), HH - 1), yc1 = min(max(y0 + 1, 0), HH - 1);
        int zc0 = min(max(z0, 0), DD - 1), zc1 = min(max(z0 + 1, 0), DD - 1);

        float wzy00 = wz0 * wy0, wzy01 = wz0 * wy1, wzy10 = wz1 * wy0, wzy11 = wz1 * wy1;
        unsigned int b00 = (zc0 * HH + yc0) * WW, b01 = (zc0 * HH + yc1) * WW;
        unsigned int b10 = (zc1 * HH + yc0) * WW, b11 = (zc1 * HH + yc1) * WW;

        uint4 vp, wp;
        vp.x = (b00 + xc0) | ((b00 + xc1) << 16);
        vp.y = (b01 + xc0) | ((b01 + xc1) << 16);
        vp.z = (b10 + xc0) | ((b10 + xc1) << 16);
        vp.w = (b11 + xc0) | ((b11 + xc1) << 16);
        wp.x = (unsigned int)f2h(wzy00 * wx0) | ((unsigned int)f2h(wzy00 * wx1) << 16);
        wp.y = (unsigned int)f2h(wzy01 * wx0) | ((unsigned int)f2h(wzy01 * wx1) << 16);
        wp.z = (unsigned int)f2h(wzy10 * wx0) | ((unsigned int)f2h(wzy10 * wx1) << 16);
        wp.w = (unsigned int)f2h(wzy11 * wx0) | ((unsigned int)f2h(wzy11 * wx1) << 16);

        unsigned int* rec = SU + si * 8;
        *(uint4*)rec       = vp;
        *(uint4*)(rec + 4) = wp;
    }

    // W fragments for tap 0 (prefetched into regs before first MFMA)
    half8 wa0 = *(const half8*)(wf + (((0 * 2 + 0) * 4 + w) << 9) + (l << 3));
    half8 wa1 = *(const half8*)(wf + (((0 * 2 + 1) * 4 + w) << 9) + (l << 3));

    __syncthreads();

    // ---- prologue: pair 0 samples tap 0 into S buf 0 ----
    if (pair == 0) {
        const unsigned int* rec = SU + sp * 8;
        const uint4 vp = *(const uint4*)rec;
        const uint4 wp = *(const uint4*)(rec + 4);
        const unsigned int vpa[4] = {vp.x, vp.y, vp.z, vp.w};
        const unsigned int wpa[4] = {wp.x, wp.y, wp.z, wp.w};
        half8 accv = {0, 0, 0, 0, 0, 0, 0, 0};
#pragma unroll
        for (int cr = 0; cr < 8; ++cr) {
            unsigned int vd = vpa[cr >> 1];
            unsigned int wd = wpa[cr >> 1];
            unsigned int voxb = ((cr & 1) ? (vd >> 16) : (vd & 0xffffu)) << 7;
            unsigned short wu = (cr & 1) ? (unsigned short)(wd >> 16) : (unsigned short)wd;
            _Float16 wh = *(_Float16*)&wu;
            const half8 v = *(const half8*)(inb + voxb + cgo);
            half8 w8 = {wh, wh, wh, wh, wh, wh, wh, wh};
            accv += v * w8;
        }
        *(half8*)(S + woff) = accv;
    }
    __syncthreads();

    // ---- main loop: sample tap k+1 (one pair) overlapped with MFMA tap k (all) ----
    int bc = 0;                                    // k % 3
    for (int k = 0; k < KN_; ++k) {
        const int kn = k + 1;
        const int bn = (bc == 2) ? 0 : bc + 1;     // kn % 3
        const bool doS = (kn < KN_) && (pair == (kn & 1));

        // issue next-tap gathers FIRST (latency hides under MFMA below)
        half8 g[8];
        uint4 wp;
        if (doS) {
            const unsigned int* rec = SU + (kn * TP + sp) * 8;
            const uint4 vp = *(const uint4*)rec;
            wp = *(const uint4*)(rec + 4);
            const unsigned int vpa[4] = {vp.x, vp.y, vp.z, vp.w};
#pragma unroll
            for (int cr = 0; cr < 8; ++cr) {
                unsigned int vd = vpa[cr >> 1];
                unsigned int voxb = ((cr & 1) ? (vd >> 16) : (vd & 0xffffu)) << 7;
                g[cr] = *(const half8*)(inb + voxb + cgo);
            }
        }

        // prefetch next-tap W fragments
        half8 nwa0 = wa0, nwa1 = wa1;
        if (kn < KN_) {
            nwa0 = *(const half8*)(wf + (((kn * 2 + 0) * 4 + w) << 9) + (l << 3));
            nwa1 = *(const half8*)(wf + (((kn * 2 + 1) * 4 + w) << 9) + (l << 3));
        }

        // MFMA tap k: D[o16 x p16] += A(o x c) * B(c x p), two 32-c chunks
        const unsigned short* Sb = S + (bc << 10);
        const half8 bf0 = *(const half8*)(Sb + roff0);
        const half8 bf1 = *(const half8*)(Sb + roff1);
        acc = __builtin_amdgcn_mfma_f32_16x16x32_f16(wa0, bf0, acc, 0, 0, 0);
        acc = __builtin_amdgcn_mfma_f32_16x16x32_f16(wa1, bf1, acc, 0, 0, 0);

        // finish sampling tap k+1 (gathers have had the MFMA phase to land)
        if (doS) {
            const unsigned int wpa[4] = {wp.x, wp.y, wp.z, wp.w};
            half8 accv = {0, 0, 0, 0, 0, 0, 0, 0};
#pragma unroll
            for (int cr = 0; cr < 8; ++cr) {
                unsigned int wd = wpa[cr >> 1];
                unsigned short wu = (cr & 1) ? (unsigned short)(wd >> 16) : (unsigned short)wd;
                _Float16 wh = *(_Float16*)&wu;
                half8 w8 = {wh, wh, wh, wh, wh, wh, wh, wh};
                accv += g[cr] * w8;
            }
            *(half8*)(S + (bn << 10) + woff) = accv;
        }

        wa0 = nwa0; wa1 = nwa1;
        bc = bn;
        __syncthreads();
    }

    // ---- epilogue: o = w*16 + lk*4 + r ; p = p0 + lrow ----
    float* ob = out + ((size_t)n * OC + (w << 4) + (lk << 2)) * DHW + p0 + lrow;
#pragma unroll
    for (int r = 0; r < 4; ++r)
        ob[r * DHW] = acc[r];
}

// ---------------------------------------------------------------------------
// Fallback (no workspace): fp32 fused kernel, original layouts.
__global__ __launch_bounds__(256) void k_fallback(const float* __restrict__ inp,
                                                  const float* __restrict__ wt,
                                                  const float* __restrict__ offs,
                                                  float* __restrict__ out) {
    __shared__ float Slds[64][68];
    __shared__ float Wlds[64 * 64];
    int bid = blockIdx.x;
    int n = bid >> 8;
    int p0 = (bid & 255) * 64;
    int t = threadIdx.x;
    int cq = t & 15, c0 = cq << 2, pslot = t >> 4;
    int ob = (t & 15) << 2, pb = (t >> 4) << 2;
    int swz_w = (((cq & 7) ^ (cq >> 3)) << 2);
    float acc[4][4] = {};
    const float* offbase = offs + (size_t)n * (KN_ * 3) * DHW;
    for (int k = 0; k < KN_; ++k) {
#pragma unroll
        for (int i = 0; i < 16; ++i) {
            int f = i * 256 + t;
            int o = f & 63, c = f >> 6;
            Wlds[f] = wt[(o * CC + c) * KN_ + k];
        }
#pragma unroll
        for (int j = 0; j < 4; ++j) {
            int pl = pslot + 16 * j;
            int pa = p0 + pl;
            int d = pa >> 10, h = (pa >> 5) & 31, w = pa & 31;
            float offz = offbase[(k * 3 + 0) * DHW + pa];
            float offy = offbase[(k * 3 + 1) * DHW + pa];
            float offx = offbase[(k * 3 + 2) * DHW + pa];
            float ix = ((float)w + offx) * (32.0f / 31.0f) - 0.5f;
            float iy = ((float)h + offy) * (32.0f / 31.0f) - 0.5f;
            float iz = ((float)d + offz) * (16.0f / 15.0f) - 0.5f;
            float xf = floorf(ix), yf = floorf(iy), zf = floorf(iz);
            float fx = ix - xf, fy = iy - yf, fz = iz - zf;
            int x0 = (int)xf, y0 = (int)yf, z0 = (int)zf;
            float wx0 = 1.0f - fx, wx1 = fx, wy0 = 1.0f - fy, wy1 = fy, wz0 = 1.0f - fz, wz1 = fz;
            float s0 = 0.f, s1 = 0.f, s2 = 0.f, s3 = 0.f;
#pragma unroll
            for (int dz = 0; dz < 2; ++dz) {
                int zc = z0 + dz;
                if ((unsigned)zc >= (unsigned)DD) continue;
                float wz = dz ? wz1 : wz0;
#pragma unroll
                for (int dy = 0; dy < 2; ++dy) {
                    int yc = y0 + dy;
                    if ((unsigned)yc >= (unsigned)HH) continue;
                    float wzy = wz * (dy ? wy1 : wy0);
#pragma unroll
                    for (int dx = 0; dx < 2; ++dx) {
                        int xc = x0 + dx;
                        if ((unsigned)xc >= (unsigned)WW) continue;
                        float wf = wzy * (dx ? wx1 : wx0);
                        int vox = (zc * HH + yc) * WW + xc;
                        const float* b = inp + (size_t)(n * CC + c0) * DHW + vox;
                        s0 += wf * b[0]; s1 += wf * b[DHW];
                        s2 += wf * b[2 * DHW]; s3 += wf * b[3 * DHW];
                    }
                }
            }
            int plw = pl ^ swz_w;
            Slds[c0 + 0][plw] = s0; Slds[c0 + 1][plw] = s1;
            Slds[c0 + 2][plw] = s2; Slds[c0 + 3][plw] = s3;
        }
        __syncthreads();
#pragma unroll
        for (int c = 0; c < 64; ++c) {
            const int g = ((c >> 2) & 7) ^ (c >> 5);
            float4 wv = *(const float4*)(Wlds + c * 64 + ob);
            float4 sv = *(const float4*)(&Slds[c][pb ^ (g << 2)]);
            float wa[4] = {wv.x, wv.y, wv.z, wv.w};
            float sa[4] = {sv.x, sv.y, sv.z, sv.w};
#pragma unroll
            for (int i = 0; i < 4; ++i)
#pragma unroll
                for (int jj = 0; jj < 4; ++jj) acc[i][jj] += wa[i] * sa[jj];
        }
        __syncthreads();
    }
#pragma unroll
    for (int i = 0; i < 4; ++i) {
        float4 vv;
        vv.x = acc[i][0]; vv.y = acc[i][1]; vv.z = acc[i][2]; vv.w = acc[i][3];
        *(float4*)(out + (size_t)(n * OC + ob + i) * DHW + p0 + pb) = vv;
    }
}

// ---------------------------------------------------------------------------
extern "C" void kernel_launch(void* const* d_in, const int* in_sizes, int n_in,
                              void* d_out, int out_size, void* d_ws, size_t ws_size,
                              hipStream_t stream) {
    const float* inp = (const float*)d_in[0];
    const float* off = (const float*)d_in[1];
    const float* wgt = (const float*)d_in[2];
    float* out = (float*)d_out;

    const size_t in_f16_bytes = (size_t)NB * DHW * CC * 2;           // 4 MB
    const size_t wf_bytes     = (size_t)KN_ * 2 * 4 * 64 * 8 * 2;    // 216 KB

    if (ws_size >= in_f16_bytes + wf_bytes) {
        unsigned int*   in_t = (unsigned int*)d_ws;
        unsigned short* w_f  = (unsigned short*)((char*)d_ws + in_f16_bytes);
        k_prep<<<dim3(512 + 432), dim3(256), 0, stream>>>(inp, wgt, in_t, w_f);
        k_main<<<dim3(2048), dim3(256), 0, stream>>>(
            (const unsigned short*)in_t, w_f, off, out);
    } else {
        k_fallback<<<dim3(NB * 256), dim3(256), 0, stream>>>(inp, wgt, off, out);
    }
}